// Round 1
// baseline (73.470 us; speedup 1.0000x reference)
//
#include <hip/hip_runtime.h>

// Problem constants (match reference)
constexpr int BS = 16, Q = 1000, NC = 80, T = 100, NI = 8;
constexpr int NP   = BS * Q;          // 16,000 predictions
constexpr int NR   = BS * T;          // 1,600 targets
constexpr int CTOT = NP * T;          // 1,600,000 C_diag entries
constexpr int ITOT = NP * NI;         //   128,000 ioa_diag entries
constexpr int C4   = CTOT / 4;        // 400,000 C-threads (4 outputs each)
constexpr int MAIN = C4 + NP;         // 416,000 main threads (exact 1625 blocks)

#define ALPHA   0.25f
#define W_CLASS 2.0f
#define W_BBOX  5.0f
#define W_GIOU  2.0f
#define LOG2E 1.44269504088896f
#define LN2   0.69314718055995f

__device__ __forceinline__ float rcp(float x)  { return __builtin_amdgcn_rcpf(x); }
__device__ __forceinline__ float ex2(float x)  { return __builtin_amdgcn_exp2f(x); }
__device__ __forceinline__ float lg2(float x)  { return __builtin_amdgcn_logf(x); }

// ---------------------------------------------------------------------------
// Pre-kernel: normalize boxes ONCE into d_ws.
//   ws[0      .. NP)   : pbn[n] = pred_boxes[n] / img_sz[b(n)]      (float4)
//   ws[NP     .. NP+NR): tbn[r] = tgt_bbox[r]   / img_sz_tgt[r]     (float4)
// These rcp's currently run 1.6M times in the hot loop; here 17.6K times.
// ---------------------------------------------------------------------------
__global__ __launch_bounds__(256) void pre_norm(
    const float* __restrict__ pred_boxes,
    const float* __restrict__ tgt_bbox,
    const float* __restrict__ img_sz,
    const float* __restrict__ img_sz_tgt,
    float4* __restrict__ ws)
{
    const int t = blockIdx.x * 256 + threadIdx.x;
    if (t < NP) {
        const int b = t / Q;
        const float4 pb = *((const float4*)pred_boxes + t);
        const float4 s  = *((const float4*)img_sz + b);
        ws[t] = make_float4(pb.x * rcp(s.x), pb.y * rcp(s.y),
                            pb.z * rcp(s.z), pb.w * rcp(s.w));
    } else if (t < NP + NR) {
        const int r = t - NP;
        const float4 tb = *((const float4*)tgt_bbox + r);
        const float4 s  = *((const float4*)img_sz_tgt + r);
        ws[NP + r] = make_float4(tb.x * rcp(s.x), tb.y * rcp(s.y),
                                 tb.z * rcp(s.z), tb.w * rcp(s.w));
    }
}

// ---------------------------------------------------------------------------
// Main kernel.
//  - C part: one thread per (n, 4 consecutive j) -> float4 store.
//    GIoU computed in NORMALIZED coords: iou and (enc-uni)/enc are exactly
//    invariant under a common per-axis scale, and img_sz rows == img_sz_tgt
//    rows by construction, so this equals the raw-coordinate GIoU.
//    Focal via softplus identity: -ln(p) = L = ln(1+e^{-x}), -ln(1-p) = x+L
//    -> 3 transcendentals (ex2, rcp, lg2) instead of 4, mathematically exact
//    (the reference's +1e-8 shifts results by <2e-6, threshold is 0.44).
//  - ioa part: one thread per n computes all 8 ignore overlaps -> 2x float4.
// ---------------------------------------------------------------------------
__global__ __launch_bounds__(256) void matcher_main(
    const float* __restrict__ pred_logits,   // (BS,Q,NC)
    const float* __restrict__ pred_boxes,    // (BS,Q,4)  raw (ioa part only)
    const float* __restrict__ ign_bbox,      // (BS*NI,4)
    const int*   __restrict__ tgt_ids,       // (BS*T,)
    const float4* __restrict__ ws,           // pbn / tbn
    float* __restrict__ out)
{
    const int idx = blockIdx.x * 256 + threadIdx.x;
    if (idx < C4) {
        const int n  = idx / 25;               // 25 threads per n (T/4)
        const int jg = (idx - n * 25) << 2;    // j group start
        const int b  = n / Q;
        const int r0 = b * T + jg;

        const float4 pbn = ws[n];
        const float area_p = (pbn.z - pbn.x) * (pbn.w - pbn.y);

        const int4 cls4 = *(const int4*)(tgt_ids + r0);   // 16B-aligned
        const float* lgp = pred_logits + (size_t)n * NC;

        float c[4];
        #pragma unroll
        for (int k = 0; k < 4; ++k) {
            const float4 tbn = ws[NP + r0 + k];
            const int   cls = (&cls4.x)[k];                // static after unroll
            const float x   = lgp[cls];

            // cost_bbox: L1 on normalized boxes
            const float cb = fabsf(pbn.x - tbn.x) + fabsf(pbn.y - tbn.y)
                           + fabsf(pbn.z - tbn.z) + fabsf(pbn.w - tbn.w);

            // focal cost, 3 transcendentals
            const float e   = ex2(-x * LOG2E);             // e^{-x}
            const float p   = rcp(1.0f + e);               // sigmoid(x)
            const float omp = e * p;                       // 1-p, exact form
            const float L   = lg2(1.0f + e) * LN2;         // -ln(p)
            const float cc  = ALPHA * omp * omp * L
                            - (1.0f - ALPHA) * p * p * (x + L);  // x+L = -ln(1-p)

            // GIoU in normalized coords
            const float area_t = (tbn.z - tbn.x) * (tbn.w - tbn.y);
            const float iw  = fminf(pbn.z, tbn.z) - fmaxf(pbn.x, tbn.x);
            const float ih  = fminf(pbn.w, tbn.w) - fmaxf(pbn.y, tbn.y);
            const float inter = fmaxf(iw, 0.0f) * fmaxf(ih, 0.0f);
            const float uni   = area_p + area_t - inter;
            const float ew  = fmaxf(pbn.z, tbn.z) - fminf(pbn.x, tbn.x);
            const float eh  = fmaxf(pbn.w, tbn.w) - fminf(pbn.y, tbn.y);
            const float enc = ew * eh;
            const float giou = inter * rcp(uni) - (enc - uni) * rcp(enc);

            c[k] = W_BBOX * cb + W_CLASS * cc - W_GIOU * giou;
        }
        *(float4*)(out + (size_t)n * T + jg) = make_float4(c[0], c[1], c[2], c[3]);
    } else {
        const int n = idx - C4;                 // one thread per prediction
        const int b = n / Q;
        const float4 pb = *((const float4*)pred_boxes + n);
        const float ra  = rcp((pb.z - pb.x) * (pb.w - pb.y));
        const float4* ib = (const float4*)ign_bbox + b * NI;
        float o[8];
        #pragma unroll
        for (int k = 0; k < 8; ++k) {
            const float4 g = ib[k];
            const float iw = fmaxf(fminf(pb.z, g.z) - fmaxf(pb.x, g.x), 0.0f);
            const float ih = fmaxf(fminf(pb.w, g.w) - fmaxf(pb.y, g.y), 0.0f);
            o[k] = iw * ih * ra;
        }
        float4* dst = (float4*)(out + CTOT + (size_t)n * NI);
        dst[0] = make_float4(o[0], o[1], o[2], o[3]);
        dst[1] = make_float4(o[4], o[5], o[6], o[7]);
    }
}

extern "C" void kernel_launch(void* const* d_in, const int* in_sizes, int n_in,
                              void* d_out, int out_size, void* d_ws, size_t ws_size,
                              hipStream_t stream) {
    const float* pred_logits = (const float*)d_in[0];
    const float* pred_boxes  = (const float*)d_in[1];
    const float* tgt_bbox    = (const float*)d_in[2];
    const float* ign_bbox    = (const float*)d_in[3];
    const float* img_sz      = (const float*)d_in[4];
    const float* img_sz_tgt  = (const float*)d_in[5];
    const int*   tgt_ids     = (const int*)d_in[6];
    float* out = (float*)d_out;

    pre_norm<<<(NP + NR + 255) / 256, 256, 0, stream>>>(
        pred_boxes, tgt_bbox, img_sz, img_sz_tgt, (float4*)d_ws);

    matcher_main<<<MAIN / 256, 256, 0, stream>>>(      // 1625 blocks, exact
        pred_logits, pred_boxes, ign_bbox, tgt_ids, (const float4*)d_ws, out);
}